// Round 13
// baseline (326.216 us; speedup 1.0000x reference)
//
#include <hip/hip_runtime.h>

static constexpr int N_GENES = 20000;
static constexpr int D       = 256;
static constexpr int NNZ     = 640000;
static constexpr int BATCH   = 16384;
static constexpr int MAXG    = 5;
static constexpr int SCAN_B  = (N_GENES + 255) / 256;   // 79

using bf16x8 = __attribute__((ext_vector_type(8))) short;
using us8    = __attribute__((ext_vector_type(8))) unsigned short;
using f32x4  = __attribute__((ext_vector_type(4))) float;

__device__ __forceinline__ unsigned short f2bf(float f) {
  unsigned int u = __builtin_bit_cast(unsigned int, f);
  u += 0x7fffu + ((u >> 16) & 1u);
  return (unsigned short)(u >> 16);
}
__device__ __forceinline__ float bf2f(unsigned short h) {
  unsigned int u = ((unsigned int)h) << 16;
  return __builtin_bit_cast(float, u);
}
__device__ __forceinline__ void gload16(const void* g, void* l) {
  __builtin_amdgcn_global_load_lds(
      (const __attribute__((address_space(1))) unsigned int*)g,
      (__attribute__((address_space(3))) unsigned int*)l, 16, 0, 0);
}

// ---------------------------------------------------------------- CSR build
// NOTE: harness delivers ALL integer inputs as int32 (even jnp.int64 ones).
__global__ void count_rows(const int* __restrict__ adj_row, int* __restrict__ cnt) {
  int e = blockIdx.x * blockDim.x + threadIdx.x;
  if (e < NNZ) atomicAdd(&cnt[adj_row[e]], 1);
}

// single-dispatch scan: block b sums preceding chunks column-wise (<=78
// coalesced loads/thread), reduces to bpre, then local scan of its chunk.
__global__ __launch_bounds__(256)
void scan_one(const int* __restrict__ cnt, int* __restrict__ row_ptr,
              int* __restrict__ fill_ctr) {
  __shared__ int s[256];
  int b = blockIdx.x, t = threadIdx.x, i = b * 256 + t;
  int pre_t = 0;
  for (int c = 0; c < b; ++c) pre_t += cnt[c * 256 + t];   // c*256+t <= 19967
  s[t] = pre_t;
  __syncthreads();
  for (int off = 128; off > 0; off >>= 1) {
    if (t < off) s[t] += s[t + off];
    __syncthreads();
  }
  int bpre = s[0];
  __syncthreads();
  int x = (i < N_GENES) ? cnt[i] : 0;
  s[t] = x;
  __syncthreads();
  for (int off = 1; off < 256; off <<= 1) {
    int v = (t >= off) ? s[t - off] : 0;
    __syncthreads();
    s[t] += v;
    __syncthreads();
  }
  if (i < N_GENES) {
    int e = bpre + s[t] - x;
    row_ptr[i] = e;
    fill_ctr[i] = e;
  }
  if (b == 0 && t == 0) row_ptr[N_GENES] = NNZ;
}

// ---------------- fused: fill_csr (blocks 0..2499) + conv_weights (2500..2627)
//                        + conv_pert (2628..7627). One dispatch, 3 independent jobs.
__global__ __launch_bounds__(256)
void fused_fill_conv(const int* __restrict__ adj_row, const int* __restrict__ adj_col,
                     const float* __restrict__ vals, int* __restrict__ fill_ctr,
                     unsigned int* __restrict__ edges,
                     const float* __restrict__ gk, const float* __restrict__ w1,
                     const float* __restrict__ w2,
                     char* __restrict__ whi, char* __restrict__ wlo,
                     const float* __restrict__ pert, ushort4* __restrict__ pert_bf) {
  int b = blockIdx.x, t = threadIdx.x;
  if (b < 2500) {
    // packed edge: low16 = col (N_GENES<65536), high16 = bf16 val
    int e = b * 256 + t;
    int r = adj_row[e];
    int p = atomicAdd(&fill_ctr[r], 1);
    edges[p] = (unsigned int)adj_col[e] | ((unsigned int)f2bf(vals[e]) << 16);
  } else if (b < 2628) {
    // weight -> bf16 hi/lo B-tile images: [nc=4][kt=4][8KB], Bs[n][k]=W[k][n],
    // XOR swizzle (byte^=(n&7)<<4 within 128B row).
    int g = (b - 2500) * 256 + t;              // 32768 threads
    int wid = g >> 13, rest = g & 8191;
    const float* W = (wid == 0) ? gk : (wid == 1) ? gk + 65536 : (wid == 2) ? w1 : w2;
    int c  = rest >> 9;
    int nc = c >> 2, kt = c & 3;
    int o  = (rest & 511) << 4;
    int n  = o >> 7;
    int wb = (o & 127) ^ ((n & 7) << 4);
    int k  = wb >> 1;
    size_t obase = ((size_t)wid << 17) + ((size_t)c << 13) + o;
    unsigned short* ph = (unsigned short*)(whi + obase);
    unsigned short* pl = (unsigned short*)(wlo + obase);
    #pragma unroll
    for (int e2 = 0; e2 < 8; ++e2) {
      float f = W[(size_t)(kt * 64 + k + e2) * 256 + nc * 64 + n];
      unsigned short h = f2bf(f);
      ph[e2] = h;
      pl[e2] = f2bf(f - bf2f(h));
    }
  } else {
    // pert -> bf16 row-major
    int i = (b - 2628) * 256 + t;              // 1.28M float4 granules
    float4 v = reinterpret_cast<const float4*>(pert)[i];
    ushort4 r4;
    r4.x = f2bf(v.x); r4.y = f2bf(v.y); r4.z = f2bf(v.z); r4.w = f2bf(v.w);
    pert_bf[i] = r4;
  }
}

// ------------------------------------------------------------- SpMM (gather)
__global__ __launch_bounds__(256)
void spmm_csr_img(const int* __restrict__ row_ptr, const unsigned int* __restrict__ edges,
                  const unsigned short* __restrict__ src,
                  char* __restrict__ hi_img, char* __restrict__ lo_img) {
  int row = blockIdx.x * 4 + (threadIdx.x >> 6);
  int lane = threadIdx.x & 63;
  int beg = row_ptr[row], end = row_ptr[row + 1];
  const unsigned short* sp = src + lane * 4;
  float4 acc = {0.f, 0.f, 0.f, 0.f};
  int j = beg;
  for (; j + 8 <= end; j += 8) {
    unsigned int e0 = edges[j],     e1 = edges[j + 1], e2 = edges[j + 2], e3 = edges[j + 3];
    unsigned int e4 = edges[j + 4], e5 = edges[j + 5], e6 = edges[j + 6], e7 = edges[j + 7];
    ushort4 g0 = *reinterpret_cast<const ushort4*>(sp + (size_t)(e0 & 0xFFFFu) * D);
    ushort4 g1 = *reinterpret_cast<const ushort4*>(sp + (size_t)(e1 & 0xFFFFu) * D);
    ushort4 g2 = *reinterpret_cast<const ushort4*>(sp + (size_t)(e2 & 0xFFFFu) * D);
    ushort4 g3 = *reinterpret_cast<const ushort4*>(sp + (size_t)(e3 & 0xFFFFu) * D);
    ushort4 g4 = *reinterpret_cast<const ushort4*>(sp + (size_t)(e4 & 0xFFFFu) * D);
    ushort4 g5 = *reinterpret_cast<const ushort4*>(sp + (size_t)(e5 & 0xFFFFu) * D);
    ushort4 g6 = *reinterpret_cast<const ushort4*>(sp + (size_t)(e6 & 0xFFFFu) * D);
    ushort4 g7 = *reinterpret_cast<const ushort4*>(sp + (size_t)(e7 & 0xFFFFu) * D);
    float v0 = bf2f(e0 >> 16), v1 = bf2f(e1 >> 16), v2 = bf2f(e2 >> 16), v3 = bf2f(e3 >> 16);
    float v4 = bf2f(e4 >> 16), v5 = bf2f(e5 >> 16), v6 = bf2f(e6 >> 16), v7 = bf2f(e7 >> 16);
    acc.x += v0 * bf2f(g0.x); acc.y += v0 * bf2f(g0.y); acc.z += v0 * bf2f(g0.z); acc.w += v0 * bf2f(g0.w);
    acc.x += v1 * bf2f(g1.x); acc.y += v1 * bf2f(g1.y); acc.z += v1 * bf2f(g1.z); acc.w += v1 * bf2f(g1.w);
    acc.x += v2 * bf2f(g2.x); acc.y += v2 * bf2f(g2.y); acc.z += v2 * bf2f(g2.z); acc.w += v2 * bf2f(g2.w);
    acc.x += v3 * bf2f(g3.x); acc.y += v3 * bf2f(g3.y); acc.z += v3 * bf2f(g3.z); acc.w += v3 * bf2f(g3.w);
    acc.x += v4 * bf2f(g4.x); acc.y += v4 * bf2f(g4.y); acc.z += v4 * bf2f(g4.z); acc.w += v4 * bf2f(g4.w);
    acc.x += v5 * bf2f(g5.x); acc.y += v5 * bf2f(g5.y); acc.z += v5 * bf2f(g5.z); acc.w += v5 * bf2f(g5.w);
    acc.x += v6 * bf2f(g6.x); acc.y += v6 * bf2f(g6.y); acc.z += v6 * bf2f(g6.z); acc.w += v6 * bf2f(g6.w);
    acc.x += v7 * bf2f(g7.x); acc.y += v7 * bf2f(g7.y); acc.z += v7 * bf2f(g7.z); acc.w += v7 * bf2f(g7.w);
  }
  for (; j < end; ++j) {
    unsigned int e = edges[j];
    ushort4 g = *reinterpret_cast<const ushort4*>(sp + (size_t)(e & 0xFFFFu) * D);
    float v = bf2f(e >> 16);
    acc.x += v * bf2f(g.x); acc.y += v * bf2f(g.y); acc.z += v * bf2f(g.z); acc.w += v * bf2f(g.w);
  }
  int mt = row >> 7, r = row & 127, kt = lane >> 4;
  int wb = ((lane & 15) << 3) ^ ((r & 7) << 4);
  size_t off = ((size_t)(mt * 4 + kt) << 14) + (size_t)r * 128 + wb;
  float a4[4] = {acc.x, acc.y, acc.z, acc.w};
  ushort4 hi, lo;
  unsigned short* ph = (unsigned short*)&hi;
  unsigned short* pl = (unsigned short*)&lo;
  #pragma unroll
  for (int e = 0; e < 4; ++e) {
    unsigned short h = f2bf(a4[e]);
    ph[e] = h;
    pl[e] = f2bf(a4[e] - bf2f(h));
  }
  *reinterpret_cast<ushort4*>(hi_img + off) = hi;
  *reinterpret_cast<ushort4*>(lo_img + off) = lo;
}

__device__ __forceinline__ int xcd_swizzle(int orig, int nwg) {
  int xcd = orig & 7, boff = orig >> 3;
  int q = nwg >> 3, r8 = nwg & 7;
  return (xcd < r8 ? xcd * (q + 1) : r8 * (q + 1) + (xcd - r8) * q) + boff;
}

// ------------------------------------------------------ bf16x3 MFMA GEMM
// BM=128, BN=128, BK=64; 4 waves (2x2), wave tile 64x64. 64KB LDS, 2 blocks/CU.
// 1D grid + bijective XCD swizzle: both nt2 col-blocks of one mt share an XCD L2.
enum Epi { E_F32, E_RELU_BF16, E_SELECT };

template <Epi EP>
__global__ __launch_bounds__(256)
void gemm_bf16x3(const char* __restrict__ Ahi, const char* __restrict__ Alo,
                 const char* __restrict__ Bhi, const char* __restrict__ Blo,
                 const float* __restrict__ bias, float* __restrict__ C,
                 unsigned short* __restrict__ Cbf,
                 const float* __restrict__ ngenes, int M) {
  __shared__ __align__(16) char smem[65536];
  char* sAh = smem;
  char* sAl = smem + 16384;
  char* sBh = smem + 32768;
  char* sBl = smem + 49152;

  const int t = threadIdx.x;
  const int w = t >> 6, l = t & 63;
  const int wr = w >> 1, wc = w & 1;
  const int wgid = xcd_swizzle(blockIdx.x, gridDim.x);
  const int mt = wgid >> 1, nt2 = wgid & 1;

  f32x4 acc[4][4] = {};
  const int rA = l & 15;
  const int kB = (l >> 4) << 4;
  const int xA = (rA & 7) << 4;

  for (int kt = 0; kt < 4; ++kt) {
    const char* gAh  = Ahi + ((size_t)(mt * 4 + kt) << 14);
    const char* gAl  = Alo + ((size_t)(mt * 4 + kt) << 14);
    const char* gBh0 = Bhi + ((size_t)((nt2 * 2 + 0) * 4 + kt) << 13);
    const char* gBl0 = Blo + ((size_t)((nt2 * 2 + 0) * 4 + kt) << 13);
    const char* gBh1 = Bhi + ((size_t)((nt2 * 2 + 1) * 4 + kt) << 13);
    const char* gBl1 = Blo + ((size_t)((nt2 * 2 + 1) * 4 + kt) << 13);
    #pragma unroll
    for (int j = 0; j < 4; ++j) {
      gload16(gAh + (j * 256 + t) * 16, sAh + j * 4096 + w * 1024);
      gload16(gAl + (j * 256 + t) * 16, sAl + j * 4096 + w * 1024);
    }
    #pragma unroll
    for (int j = 0; j < 2; ++j) {
      gload16(gBh0 + (j * 256 + t) * 16, sBh + j * 4096 + w * 1024);
      gload16(gBl0 + (j * 256 + t) * 16, sBl + j * 4096 + w * 1024);
      gload16(gBh1 + (j * 256 + t) * 16, sBh + 8192 + j * 4096 + w * 1024);
      gload16(gBl1 + (j * 256 + t) * 16, sBl + 8192 + j * 4096 + w * 1024);
    }
    asm volatile("s_waitcnt vmcnt(0)" ::: "memory");
    __syncthreads();
    #pragma unroll
    for (int ks = 0; ks < 2; ++ks) {
      bf16x8 ah[4], al[4], bh[4], bl[4];
      #pragma unroll
      for (int i = 0; i < 4; ++i) {
        int off = (wr * 64 + i * 16 + rA) * 128 + ((ks * 64 + kB) ^ xA);
        ah[i] = *(const bf16x8*)(sAh + off);
        al[i] = *(const bf16x8*)(sAl + off);
      }
      #pragma unroll
      for (int j = 0; j < 4; ++j) {
        int off = (wc * 64 + j * 16 + rA) * 128 + ((ks * 64 + kB) ^ xA);
        bh[j] = *(const bf16x8*)(sBh + off);
        bl[j] = *(const bf16x8*)(sBl + off);
      }
      #pragma unroll
      for (int i = 0; i < 4; ++i)
        #pragma unroll
        for (int j = 0; j < 4; ++j) {
          acc[i][j] = __builtin_amdgcn_mfma_f32_16x16x32_bf16(ah[i], bh[j], acc[i][j], 0, 0, 0);
          acc[i][j] = __builtin_amdgcn_mfma_f32_16x16x32_bf16(ah[i], bl[j], acc[i][j], 0, 0, 0);
          acc[i][j] = __builtin_amdgcn_mfma_f32_16x16x32_bf16(al[i], bh[j], acc[i][j], 0, 0, 0);
        }
    }
    __syncthreads();
  }

  const int cr = (l >> 4) << 2;
  const int cc = l & 15;
  #pragma unroll
  for (int i = 0; i < 4; ++i) {
    #pragma unroll
    for (int rr = 0; rr < 4; ++rr) {
      int rin  = wr * 64 + i * 16 + cr + rr;
      int grow = mt * 128 + rin;
      if (grow >= M) continue;
      bool wr_row = true;
      if (EP == E_SELECT) wr_row = (ngenes[grow] >= 1.5f);
      #pragma unroll
      for (int j = 0; j < 4; ++j) {
        float v   = acc[i][j][rr];
        int gcol  = nt2 * 128 + wc * 64 + j * 16 + cc;
        if (EP == E_SELECT) v += bias[gcol];
        if (EP != E_F32) v = fmaxf(v, 0.f);
        if (EP == E_RELU_BF16) {
          Cbf[(size_t)grow * 256 + gcol] = f2bf(v);
        } else if (wr_row) {
          C[(size_t)grow * 256 + gcol] = v;
        }
      }
    }
  }
}

// ------------------- MLP1 GEMM with fused condition-gather A-staging [E_HIMG]
// A-tile built in-kernel: each thread gathers 32 cols of one batch row's summed
// embedding (fp32, order g=0..4 — bit-identical to the old gather kernel),
// writes summed->d_out + ngenes (nt2==0 only), and stages swizzled bf16 hi/lo
// A via ds_write. B from weight images. Epilogue writes h images (bias+relu).
__global__ __launch_bounds__(256)
void gemm_mlp1(const int* __restrict__ cond_idx, const int* __restrict__ cg_idx,
               const float* __restrict__ cg_mask, const float* __restrict__ embf,
               const char* __restrict__ Bhi, const char* __restrict__ Blo,
               const float* __restrict__ bias, float* __restrict__ out,
               float* __restrict__ ngenes,
               char* __restrict__ Ohi, char* __restrict__ Olo) {
  __shared__ __align__(16) char smem[65536];
  char* sAh = smem;
  char* sAl = smem + 16384;
  char* sBh = smem + 32768;
  char* sBl = smem + 49152;

  const int t = threadIdx.x;
  const int w = t >> 6, l = t & 63;
  const int wr = w >> 1, wc = w & 1;
  const int wgid = xcd_swizzle(blockIdx.x, gridDim.x);
  const int mt = wgid >> 1, nt2 = wgid & 1;

  // gather identity for this thread (row r, 32-col half)
  const int gr = t >> 1, ghalf = t & 1;
  const int grow = mt * 128 + gr;
  const int gc = cond_idx[grow];

  f32x4 acc[4][4] = {};
  const int rA = l & 15;
  const int kB = (l >> 4) << 4;
  const int xA = (rA & 7) << 4;

  for (int kt = 0; kt < 4; ++kt) {
    const char* gBh0 = Bhi + ((size_t)((nt2 * 2 + 0) * 4 + kt) << 13);
    const char* gBl0 = Blo + ((size_t)((nt2 * 2 + 0) * 4 + kt) << 13);
    const char* gBh1 = Bhi + ((size_t)((nt2 * 2 + 1) * 4 + kt) << 13);
    const char* gBl1 = Blo + ((size_t)((nt2 * 2 + 1) * 4 + kt) << 13);
    #pragma unroll
    for (int j = 0; j < 2; ++j) {
      gload16(gBh0 + (j * 256 + t) * 16, sBh + j * 4096 + w * 1024);
      gload16(gBl0 + (j * 256 + t) * 16, sBl + j * 4096 + w * 1024);
      gload16(gBh1 + (j * 256 + t) * 16, sBh + 8192 + j * 4096 + w * 1024);
      gload16(gBl1 + (j * 256 + t) * 16, sBl + 8192 + j * 4096 + w * 1024);
    }
    // gather this kt's 64-col slice for row gr (32 cols per thread)
    float4 a[8] = {};
    float n = 0.f;
    #pragma unroll
    for (int g = 0; g < MAXG; ++g) {
      float m = cg_mask[gc * MAXG + g];
      n += m;
      if (m > 0.f) {
        const float4* e = reinterpret_cast<const float4*>(
            embf + (size_t)cg_idx[gc * MAXG + g] * 256 + kt * 64 + ghalf * 32);
        #pragma unroll
        for (int q = 0; q < 8; ++q) {
          float4 ev = e[q];
          a[q].x += m * ev.x; a[q].y += m * ev.y;
          a[q].z += m * ev.z; a[q].w += m * ev.w;
        }
      }
    }
    if (nt2 == 0) {
      float4* o = reinterpret_cast<float4*>(out + (size_t)grow * 256 + kt * 64 + ghalf * 32);
      #pragma unroll
      for (int q = 0; q < 8; ++q) o[q] = a[q];
      if (kt == 0 && ghalf == 0) ngenes[grow] = n;
    }
    // bf16 hi/lo split + swizzled LDS write (4x 16B granules each)
    const int xr = (gr & 7) << 4;
    const float* av = reinterpret_cast<const float*>(a);
    #pragma unroll
    for (int q = 0; q < 4; ++q) {
      us8 hv, lv;
      #pragma unroll
      for (int jj = 0; jj < 8; ++jj) {
        float vv = av[q * 8 + jj];
        unsigned short h = f2bf(vv);
        hv[jj] = h;
        lv[jj] = f2bf(vv - bf2f(h));
      }
      int byteoff = gr * 128 + (((ghalf * 32 + q * 8) << 1) ^ xr);
      *reinterpret_cast<us8*>(sAh + byteoff) = hv;
      *reinterpret_cast<us8*>(sAl + byteoff) = lv;
    }
    asm volatile("s_waitcnt vmcnt(0)" ::: "memory");
    __syncthreads();
    #pragma unroll
    for (int ks = 0; ks < 2; ++ks) {
      bf16x8 ah[4], al[4], bh[4], bl[4];
      #pragma unroll
      for (int i = 0; i < 4; ++i) {
        int off = (wr * 64 + i * 16 + rA) * 128 + ((ks * 64 + kB) ^ xA);
        ah[i] = *(const bf16x8*)(sAh + off);
        al[i] = *(const bf16x8*)(sAl + off);
      }
      #pragma unroll
      for (int j = 0; j < 4; ++j) {
        int off = (wc * 64 + j * 16 + rA) * 128 + ((ks * 64 + kB) ^ xA);
        bh[j] = *(const bf16x8*)(sBh + off);
        bl[j] = *(const bf16x8*)(sBl + off);
      }
      #pragma unroll
      for (int i = 0; i < 4; ++i)
        #pragma unroll
        for (int j = 0; j < 4; ++j) {
          acc[i][j] = __builtin_amdgcn_mfma_f32_16x16x32_bf16(ah[i], bh[j], acc[i][j], 0, 0, 0);
          acc[i][j] = __builtin_amdgcn_mfma_f32_16x16x32_bf16(ah[i], bl[j], acc[i][j], 0, 0, 0);
          acc[i][j] = __builtin_amdgcn_mfma_f32_16x16x32_bf16(al[i], bh[j], acc[i][j], 0, 0, 0);
        }
    }
    __syncthreads();
  }

  // epilogue: h = relu(v + bias) -> A-image for MLP2
  const int cr = (l >> 4) << 2;
  const int cc = l & 15;
  #pragma unroll
  for (int i = 0; i < 4; ++i) {
    #pragma unroll
    for (int rr = 0; rr < 4; ++rr) {
      int rin = wr * 64 + i * 16 + cr + rr;
      #pragma unroll
      for (int j = 0; j < 4; ++j) {
        float v   = acc[i][j][rr];
        int colin = wc * 64 + j * 16 + cc;
        int gcol  = nt2 * 128 + colin;
        v = fmaxf(v + bias[gcol], 0.f);
        int kt2 = nt2 * 2 + (colin >> 6);
        int k2  = colin & 63;
        int wb  = (k2 << 1) ^ ((rin & 7) << 4);
        size_t off = ((size_t)(mt * 4 + kt2) << 14) + (size_t)rin * 128 + wb;
        unsigned short h16 = f2bf(v);
        *(unsigned short*)(Ohi + off) = h16;
        *(unsigned short*)(Olo + off) = f2bf(v - bf2f(h16));
      }
    }
  }
}

// ---------------------------------------------------------------- launch
extern "C" void kernel_launch(void* const* d_in, const int* in_sizes, int n_in,
                              void* d_out, int out_size, void* d_ws, size_t ws_size,
                              hipStream_t stream) {
  const int*   cond_idx = (const int*)d_in[0];
  const float* pert     = (const float*)d_in[1];
  const float* gnn_k    = (const float*)d_in[2];
  const float* w1       = (const float*)d_in[3];
  const float* b1       = (const float*)d_in[4];
  const float* w2       = (const float*)d_in[5];
  const float* b2       = (const float*)d_in[6];
  const int*   adj_row  = (const int*)d_in[7];   // int32! harness demotes int64
  const int*   adj_col  = (const int*)d_in[8];   // int32!
  const float* adj_vals = (const float*)d_in[9];
  const int*   cg_idx   = (const int*)d_in[10];
  const float* cg_mask  = (const float*)d_in[11];
  float* out = (float*)d_out;

  char* w = (char*)d_ws;
  auto alloc = [&](size_t bytes) {
    void* p = w;
    w += (bytes + 255) & ~size_t(255);
    return p;
  };
  constexpr int MT_G = (N_GENES + 127) / 128;   // 157
  constexpr int MT_B = BATCH / 128;             // 128
  char*         aggHi   = (char*)alloc((size_t)MT_G * 4 * 16384);   // 10.3 MB
  char*         aggLo   = (char*)alloc((size_t)MT_G * 4 * 16384);
  float*        embf    = (float*)alloc((size_t)N_GENES * D * 4);   // 20.5 MB
  char*         hHi     = (char*)alloc((size_t)MT_B * 4 * 16384);   // 8.4 MB
  char*         hLo     = (char*)alloc((size_t)MT_B * 4 * 16384);
  char*         wHi     = (char*)alloc((size_t)4 << 17);            // 512 KB
  char*         wLo     = (char*)alloc((size_t)4 << 17);
  unsigned int* edges   = (unsigned int*)alloc((size_t)NNZ * 4);    // 2.56 MB
  int*          cnt     = (int*)alloc((size_t)N_GENES * 4);
  int*          row_ptr = (int*)alloc((size_t)(N_GENES + 4) * 4);
  int*          fill_ctr= (int*)alloc((size_t)N_GENES * 4);
  float*        ngenes  = (float*)alloc((size_t)BATCH * 4);
  char*         pertbf_buf = (char*)alloc((size_t)N_GENES * D * 2); // 10.25 MB

  unsigned short* pert_bf = (unsigned short*)pertbf_buf;
  // embf_bf aliases embf: written step-3 gemm, read step-4 spmm; embf fp32
  // rewritten by step-4 gemm (stream-ordered after).
  unsigned short* embf_bf = (unsigned short*)embf;

  // 1. CSR build + conversions (10 graph nodes total)
  hipMemsetAsync(cnt, 0, (size_t)N_GENES * 4, stream);
  count_rows<<<NNZ / 256, 256, 0, stream>>>(adj_row, cnt);
  scan_one<<<SCAN_B, 256, 0, stream>>>(cnt, row_ptr, fill_ctr);
  fused_fill_conv<<<2500 + 128 + 5000, 256, 0, stream>>>(
      adj_row, adj_col, adj_vals, fill_ctr, edges,
      gnn_k, w1, w2, wHi, wLo, pert, (ushort4*)pert_bf);

  // 3. GNN layer 0: agg = A@pert_bf (images); emb1 = relu(agg @ K0) -> bf16
  spmm_csr_img<<<N_GENES / 4, 256, 0, stream>>>(row_ptr, edges, pert_bf, aggHi, aggLo);
  gemm_bf16x3<E_RELU_BF16><<<2 * MT_G, 256, 0, stream>>>(
      aggHi, aggLo, wHi, wLo, nullptr, nullptr, embf_bf, nullptr, N_GENES);

  // 4. GNN layer 1: agg = A@emb1_bf (images); emb2 = agg @ K1 -> fp32
  spmm_csr_img<<<N_GENES / 4, 256, 0, stream>>>(row_ptr, edges, embf_bf, aggHi, aggLo);
  gemm_bf16x3<E_F32><<<2 * MT_G, 256, 0, stream>>>(
      aggHi, aggLo, wHi + (1 << 17), wLo + (1 << 17), nullptr, embf, nullptr, nullptr, N_GENES);

  // 6. MLP1 (+fused condition gather): summed->d_out, ngenes,
  //    h = relu(summed@W1+b1) -> h images
  gemm_mlp1<<<2 * MT_B, 256, 0, stream>>>(
      cond_idx, cg_idx, cg_mask, embf, wHi + (2 << 17), wLo + (2 << 17),
      b1, out, ngenes, hHi, hLo);

  // 7. MLP2: rows with n>=2 get relu(h@W2+b2)
  gemm_bf16x3<E_SELECT><<<2 * MT_B, 256, 0, stream>>>(
      hHi, hLo, wHi + (3 << 17), wLo + (3 << 17), b2, out, nullptr, ngenes, BATCH);
}

// Round 14
// 313.232 us; speedup vs baseline: 1.0415x; 1.0415x over previous
//
#include <hip/hip_runtime.h>

static constexpr int N_GENES = 20000;
static constexpr int D       = 256;
static constexpr int NNZ     = 640000;
static constexpr int BATCH   = 16384;
static constexpr int MAXG    = 5;
static constexpr int NR      = 8;                // col-ranges of 2560 cols (1.25MB bf16 slice)
static constexpr int NB      = N_GENES * NR;     // 160000 buckets
static constexpr int SCAN_BLKS = NB / 256;       // 625

using bf16x8 = __attribute__((ext_vector_type(8))) short;
using f32x4  = __attribute__((ext_vector_type(4))) float;

__device__ __forceinline__ unsigned short f2bf(float f) {
  unsigned int u = __builtin_bit_cast(unsigned int, f);
  u += 0x7fffu + ((u >> 16) & 1u);
  return (unsigned short)(u >> 16);
}
__device__ __forceinline__ float bf2f(unsigned short h) {
  unsigned int u = ((unsigned int)h) << 16;
  return __builtin_bit_cast(float, u);
}
__device__ __forceinline__ void gload16(const void* g, void* l) {
  __builtin_amdgcn_global_load_lds(
      (const __attribute__((address_space(1))) unsigned int*)g,
      (__attribute__((address_space(3))) unsigned int*)l, 16, 0, 0);
}
// col/2560 for col<20000 (verified at boundaries 2559/2560/5119/5120/.../19999)
__device__ __forceinline__ unsigned colrange(int col) {
  return ((unsigned)col * 26215u) >> 26;
}

// ---------------------------------------------------------------- CSR build
// NOTE: harness delivers ALL integer inputs as int32 (even jnp.int64 ones).
__global__ void count_buckets(const int* __restrict__ adj_row,
                              const int* __restrict__ adj_col, int* __restrict__ cnt) {
  int e = blockIdx.x * 256 + threadIdx.x;        // grid = NNZ/256 exact
  int r = adj_row[e];
  atomicAdd(&cnt[(r << 3) | colrange(adj_col[e])], 1);
}

__global__ __launch_bounds__(256)
void scan_partial(const int* __restrict__ cnt, int* __restrict__ bsum) {
  __shared__ int red[256];
  int b = blockIdx.x, t = threadIdx.x;
  red[t] = cnt[b * 256 + t];                     // NB = 625*256 exact
  __syncthreads();
  for (int off = 128; off > 0; off >>= 1) {
    if (t < off) red[t] += red[t + off];
    __syncthreads();
  }
  if (t == 0) bsum[b] = red[0];
}

__global__ __launch_bounds__(1024)
void scan_mid(const int* __restrict__ bsum, int* __restrict__ bpre) {
  __shared__ int s[1024];
  int t = threadIdx.x;
  int x = (t < SCAN_BLKS) ? bsum[t] : 0;
  s[t] = x;
  __syncthreads();
  for (int off = 1; off < 1024; off <<= 1) {
    int v = (t >= off) ? s[t - off] : 0;
    __syncthreads();
    s[t] += v;
    __syncthreads();
  }
  if (t < SCAN_BLKS) bpre[t] = s[t] - x;         // exclusive prefix
}

__global__ __launch_bounds__(256)
void scan_final(const int* __restrict__ cnt, const int* __restrict__ bpre,
                int* __restrict__ bptr, int* __restrict__ fill_ctr) {
  __shared__ int s[256];
  int b = blockIdx.x, t = threadIdx.x, i = b * 256 + t;
  int x = cnt[i];
  s[t] = x;
  __syncthreads();
  for (int off = 1; off < 256; off <<= 1) {
    int v = (t >= off) ? s[t - off] : 0;
    __syncthreads();
    s[t] += v;
    __syncthreads();
  }
  int e = bpre[b] + s[t] - x;
  bptr[i] = e;
  fill_ctr[i] = e;
  if (b == 0 && t == 0) bptr[NB] = NNZ;
}

// ---------------- fused: fill_csr (blocks 0..2499) + conv_weights (2500..2627)
//                        + conv_pert (2628..7627). One dispatch, 3 independent jobs.
__global__ __launch_bounds__(256)
void fused_fill_conv(const int* __restrict__ adj_row, const int* __restrict__ adj_col,
                     const float* __restrict__ vals, int* __restrict__ fill_ctr,
                     unsigned int* __restrict__ edges,
                     const float* __restrict__ gk, const float* __restrict__ w1,
                     const float* __restrict__ w2,
                     char* __restrict__ whi, char* __restrict__ wlo,
                     const float* __restrict__ pert, ushort4* __restrict__ pert_bf) {
  int b = blockIdx.x, t = threadIdx.x;
  if (b < 2500) {
    // packed edge: low16 = col (N_GENES<65536), high16 = bf16 val;
    // bucket = (row, col-range) so each row's edges end up range-sorted.
    int e = b * 256 + t;
    int r = adj_row[e];
    int col = adj_col[e];
    int p = atomicAdd(&fill_ctr[(r << 3) | colrange(col)], 1);
    edges[p] = (unsigned int)col | ((unsigned int)f2bf(vals[e]) << 16);
  } else if (b < 2628) {
    // weight -> bf16 hi/lo B-tile images: [nc=4][kt=4][8KB], Bs[n][k]=W[k][n],
    // XOR swizzle (byte^=(n&7)<<4 within 128B row).
    int g = (b - 2500) * 256 + t;
    int wid = g >> 13, rest = g & 8191;
    const float* W = (wid == 0) ? gk : (wid == 1) ? gk + 65536 : (wid == 2) ? w1 : w2;
    int c  = rest >> 9;
    int nc = c >> 2, kt = c & 3;
    int o  = (rest & 511) << 4;
    int n  = o >> 7;
    int wb = (o & 127) ^ ((n & 7) << 4);
    int k  = wb >> 1;
    size_t obase = ((size_t)wid << 17) + ((size_t)c << 13) + o;
    unsigned short* ph = (unsigned short*)(whi + obase);
    unsigned short* pl = (unsigned short*)(wlo + obase);
    #pragma unroll
    for (int e2 = 0; e2 < 8; ++e2) {
      float f = W[(size_t)(kt * 64 + k + e2) * 256 + nc * 64 + n];
      unsigned short h = f2bf(f);
      ph[e2] = h;
      pl[e2] = f2bf(f - bf2f(h));
    }
  } else {
    // pert -> bf16 row-major
    int i = (b - 2628) * 256 + t;
    float4 v = reinterpret_cast<const float4*>(pert)[i];
    ushort4 r4;
    r4.x = f2bf(v.x); r4.y = f2bf(v.y); r4.z = f2bf(v.z); r4.w = f2bf(v.w);
    pert_bf[i] = r4;
  }
}

// ------------------------------------------------------------- SpMM (gather)
// one wave per gene row; edges range-sorted -> resident waves sweep col-ranges
// in phase, keeping the active 1.25MB src slice L2-hot. 8 gathers in flight.
__global__ __launch_bounds__(256)
void spmm_csr_img(const int* __restrict__ bptr, const unsigned int* __restrict__ edges,
                  const unsigned short* __restrict__ src,
                  char* __restrict__ hi_img, char* __restrict__ lo_img) {
  int row = blockIdx.x * 4 + (threadIdx.x >> 6);
  int lane = threadIdx.x & 63;
  int beg = bptr[row << 3], end = bptr[(row << 3) + 8];
  const unsigned short* sp = src + lane * 4;
  float4 acc = {0.f, 0.f, 0.f, 0.f};
  int j = beg;
  for (; j + 8 <= end; j += 8) {
    unsigned int e0 = edges[j],     e1 = edges[j + 1], e2 = edges[j + 2], e3 = edges[j + 3];
    unsigned int e4 = edges[j + 4], e5 = edges[j + 5], e6 = edges[j + 6], e7 = edges[j + 7];
    ushort4 g0 = *reinterpret_cast<const ushort4*>(sp + (size_t)(e0 & 0xFFFFu) * D);
    ushort4 g1 = *reinterpret_cast<const ushort4*>(sp + (size_t)(e1 & 0xFFFFu) * D);
    ushort4 g2 = *reinterpret_cast<const ushort4*>(sp + (size_t)(e2 & 0xFFFFu) * D);
    ushort4 g3 = *reinterpret_cast<const ushort4*>(sp + (size_t)(e3 & 0xFFFFu) * D);
    ushort4 g4 = *reinterpret_cast<const ushort4*>(sp + (size_t)(e4 & 0xFFFFu) * D);
    ushort4 g5 = *reinterpret_cast<const ushort4*>(sp + (size_t)(e5 & 0xFFFFu) * D);
    ushort4 g6 = *reinterpret_cast<const ushort4*>(sp + (size_t)(e6 & 0xFFFFu) * D);
    ushort4 g7 = *reinterpret_cast<const ushort4*>(sp + (size_t)(e7 & 0xFFFFu) * D);
    float v0 = bf2f(e0 >> 16), v1 = bf2f(e1 >> 16), v2 = bf2f(e2 >> 16), v3 = bf2f(e3 >> 16);
    float v4 = bf2f(e4 >> 16), v5 = bf2f(e5 >> 16), v6 = bf2f(e6 >> 16), v7 = bf2f(e7 >> 16);
    acc.x += v0 * bf2f(g0.x); acc.y += v0 * bf2f(g0.y); acc.z += v0 * bf2f(g0.z); acc.w += v0 * bf2f(g0.w);
    acc.x += v1 * bf2f(g1.x); acc.y += v1 * bf2f(g1.y); acc.z += v1 * bf2f(g1.z); acc.w += v1 * bf2f(g1.w);
    acc.x += v2 * bf2f(g2.x); acc.y += v2 * bf2f(g2.y); acc.z += v2 * bf2f(g2.z); acc.w += v2 * bf2f(g2.w);
    acc.x += v3 * bf2f(g3.x); acc.y += v3 * bf2f(g3.y); acc.z += v3 * bf2f(g3.z); acc.w += v3 * bf2f(g3.w);
    acc.x += v4 * bf2f(g4.x); acc.y += v4 * bf2f(g4.y); acc.z += v4 * bf2f(g4.z); acc.w += v4 * bf2f(g4.w);
    acc.x += v5 * bf2f(g5.x); acc.y += v5 * bf2f(g5.y); acc.z += v5 * bf2f(g5.z); acc.w += v5 * bf2f(g5.w);
    acc.x += v6 * bf2f(g6.x); acc.y += v6 * bf2f(g6.y); acc.z += v6 * bf2f(g6.z); acc.w += v6 * bf2f(g6.w);
    acc.x += v7 * bf2f(g7.x); acc.y += v7 * bf2f(g7.y); acc.z += v7 * bf2f(g7.z); acc.w += v7 * bf2f(g7.w);
  }
  for (; j < end; ++j) {
    unsigned int e = edges[j];
    ushort4 g = *reinterpret_cast<const ushort4*>(sp + (size_t)(e & 0xFFFFu) * D);
    float v = bf2f(e >> 16);
    acc.x += v * bf2f(g.x); acc.y += v * bf2f(g.y); acc.z += v * bf2f(g.z); acc.w += v * bf2f(g.w);
  }
  int mt = row >> 7, r = row & 127, kt = lane >> 4;
  int wb = ((lane & 15) << 3) ^ ((r & 7) << 4);
  size_t off = ((size_t)(mt * 4 + kt) << 14) + (size_t)r * 128 + wb;
  float a4[4] = {acc.x, acc.y, acc.z, acc.w};
  ushort4 hi, lo;
  unsigned short* ph = (unsigned short*)&hi;
  unsigned short* pl = (unsigned short*)&lo;
  #pragma unroll
  for (int e = 0; e < 4; ++e) {
    unsigned short h = f2bf(a4[e]);
    ph[e] = h;
    pl[e] = f2bf(a4[e] - bf2f(h));
  }
  *reinterpret_cast<ushort4*>(hi_img + off) = hi;
  *reinterpret_cast<ushort4*>(lo_img + off) = lo;
}

// ------------------------------------------------- condition gather (summed)
// (standalone again — round-13 fusion into MLP1 regressed: 2x redundant gather
//  serialized at 2 blocks/CU. Here it runs at 4096-block occupancy.)
__global__ __launch_bounds__(256)
void gather_conditions(const int* __restrict__ cond_idx, const int* __restrict__ cg_idx,
                       const float* __restrict__ cg_mask, const float* __restrict__ emb,
                       float* __restrict__ out, char* __restrict__ hi_img,
                       char* __restrict__ lo_img, float* __restrict__ ngenes) {
  int b = blockIdx.x * 4 + (threadIdx.x >> 6);
  int lane = threadIdx.x & 63;
  int c = cond_idx[b];
  float4 acc = {0.f, 0.f, 0.f, 0.f};
  float n = 0.f;
  #pragma unroll
  for (int g = 0; g < MAXG; ++g) {
    float m = cg_mask[c * MAXG + g];
    n += m;
    if (m > 0.f) {
      int gi = cg_idx[c * MAXG + g];
      float4 e = *reinterpret_cast<const float4*>(emb + (size_t)gi * D + lane * 4);
      acc.x += m * e.x; acc.y += m * e.y; acc.z += m * e.z; acc.w += m * e.w;
    }
  }
  *reinterpret_cast<float4*>(out + (size_t)b * D + lane * 4) = acc;
  int mt = b >> 7, r = b & 127, kt = lane >> 4;
  int wb = ((lane & 15) << 3) ^ ((r & 7) << 4);
  size_t off = ((size_t)(mt * 4 + kt) << 14) + (size_t)r * 128 + wb;
  float a4[4] = {acc.x, acc.y, acc.z, acc.w};
  ushort4 hi, lo;
  unsigned short* ph = (unsigned short*)&hi;
  unsigned short* pl = (unsigned short*)&lo;
  #pragma unroll
  for (int e = 0; e < 4; ++e) {
    unsigned short h = f2bf(a4[e]);
    ph[e] = h;
    pl[e] = f2bf(a4[e] - bf2f(h));
  }
  *reinterpret_cast<ushort4*>(hi_img + off) = hi;
  *reinterpret_cast<ushort4*>(lo_img + off) = lo;
  if (lane == 0) ngenes[b] = n;
}

__device__ __forceinline__ int xcd_swizzle(int orig, int nwg) {
  int xcd = orig & 7, boff = orig >> 3;
  int q = nwg >> 3, r8 = nwg & 7;
  return (xcd < r8 ? xcd * (q + 1) : r8 * (q + 1) + (xcd - r8) * q) + boff;
}

// ------------------------------------------------------ bf16x3 MFMA GEMM
// BM=128, BN=128, BK=64; 4 waves (2x2), wave tile 64x64. 64KB LDS, 2 blocks/CU.
// 1D grid + bijective XCD swizzle: both nt2 col-blocks of one mt share an XCD L2.
enum Epi { E_F32, E_RELU_BF16, E_HIMG, E_SELECT };

template <Epi EP>
__global__ __launch_bounds__(256)
void gemm_bf16x3(const char* __restrict__ Ahi, const char* __restrict__ Alo,
                 const char* __restrict__ Bhi, const char* __restrict__ Blo,
                 const float* __restrict__ bias, float* __restrict__ C,
                 unsigned short* __restrict__ Cbf,
                 char* __restrict__ Ohi, char* __restrict__ Olo,
                 const float* __restrict__ ngenes, int M) {
  __shared__ __align__(16) char smem[65536];
  char* sAh = smem;
  char* sAl = smem + 16384;
  char* sBh = smem + 32768;
  char* sBl = smem + 49152;

  const int t = threadIdx.x;
  const int w = t >> 6, l = t & 63;
  const int wr = w >> 1, wc = w & 1;
  const int wgid = xcd_swizzle(blockIdx.x, gridDim.x);
  const int mt = wgid >> 1, nt2 = wgid & 1;

  f32x4 acc[4][4] = {};
  const int rA = l & 15;
  const int kB = (l >> 4) << 4;
  const int xA = (rA & 7) << 4;

  for (int kt = 0; kt < 4; ++kt) {
    const char* gAh  = Ahi + ((size_t)(mt * 4 + kt) << 14);
    const char* gAl  = Alo + ((size_t)(mt * 4 + kt) << 14);
    const char* gBh0 = Bhi + ((size_t)((nt2 * 2 + 0) * 4 + kt) << 13);
    const char* gBl0 = Blo + ((size_t)((nt2 * 2 + 0) * 4 + kt) << 13);
    const char* gBh1 = Bhi + ((size_t)((nt2 * 2 + 1) * 4 + kt) << 13);
    const char* gBl1 = Blo + ((size_t)((nt2 * 2 + 1) * 4 + kt) << 13);
    #pragma unroll
    for (int j = 0; j < 4; ++j) {
      gload16(gAh + (j * 256 + t) * 16, sAh + j * 4096 + w * 1024);
      gload16(gAl + (j * 256 + t) * 16, sAl + j * 4096 + w * 1024);
    }
    #pragma unroll
    for (int j = 0; j < 2; ++j) {
      gload16(gBh0 + (j * 256 + t) * 16, sBh + j * 4096 + w * 1024);
      gload16(gBl0 + (j * 256 + t) * 16, sBl + j * 4096 + w * 1024);
      gload16(gBh1 + (j * 256 + t) * 16, sBh + 8192 + j * 4096 + w * 1024);
      gload16(gBl1 + (j * 256 + t) * 16, sBl + 8192 + j * 4096 + w * 1024);
    }
    asm volatile("s_waitcnt vmcnt(0)" ::: "memory");
    __syncthreads();
    #pragma unroll
    for (int ks = 0; ks < 2; ++ks) {
      bf16x8 ah[4], al[4], bh[4], bl[4];
      #pragma unroll
      for (int i = 0; i < 4; ++i) {
        int off = (wr * 64 + i * 16 + rA) * 128 + ((ks * 64 + kB) ^ xA);
        ah[i] = *(const bf16x8*)(sAh + off);
        al[i] = *(const bf16x8*)(sAl + off);
      }
      #pragma unroll
      for (int j = 0; j < 4; ++j) {
        int off = (wc * 64 + j * 16 + rA) * 128 + ((ks * 64 + kB) ^ xA);
        bh[j] = *(const bf16x8*)(sBh + off);
        bl[j] = *(const bf16x8*)(sBl + off);
      }
      #pragma unroll
      for (int i = 0; i < 4; ++i)
        #pragma unroll
        for (int j = 0; j < 4; ++j) {
          acc[i][j] = __builtin_amdgcn_mfma_f32_16x16x32_bf16(ah[i], bh[j], acc[i][j], 0, 0, 0);
          acc[i][j] = __builtin_amdgcn_mfma_f32_16x16x32_bf16(ah[i], bl[j], acc[i][j], 0, 0, 0);
          acc[i][j] = __builtin_amdgcn_mfma_f32_16x16x32_bf16(al[i], bh[j], acc[i][j], 0, 0, 0);
        }
    }
    __syncthreads();
  }

  // epilogue. C/D frag: col = l&15, row = (l>>4)*4 + rr  [m89/m91]
  const int cr = (l >> 4) << 2;
  const int cc = l & 15;
  #pragma unroll
  for (int i = 0; i < 4; ++i) {
    #pragma unroll
    for (int rr = 0; rr < 4; ++rr) {
      int rin  = wr * 64 + i * 16 + cr + rr;
      int grow = mt * 128 + rin;
      if (grow >= M) continue;
      bool wr_row = true;
      if (EP == E_SELECT) wr_row = (ngenes[grow] >= 1.5f);
      #pragma unroll
      for (int j = 0; j < 4; ++j) {
        float v   = acc[i][j][rr];
        int colin = wc * 64 + j * 16 + cc;
        int gcol  = nt2 * 128 + colin;
        if (EP == E_HIMG || EP == E_SELECT) v += bias[gcol];
        if (EP != E_F32) v = fmaxf(v, 0.f);
        if (EP == E_HIMG) {
          int kt2 = nt2 * 2 + (colin >> 6);
          int k2  = colin & 63;
          int wb  = (k2 << 1) ^ ((rin & 7) << 4);
          size_t off = ((size_t)(mt * 4 + kt2) << 14) + (size_t)rin * 128 + wb;
          unsigned short h16 = f2bf(v);
          *(unsigned short*)(Ohi + off) = h16;
          *(unsigned short*)(Olo + off) = f2bf(v - bf2f(h16));
        } else if (EP == E_RELU_BF16) {
          Cbf[(size_t)grow * 256 + gcol] = f2bf(v);
        } else if (wr_row) {
          C[(size_t)grow * 256 + gcol] = v;
        }
      }
    }
  }
}

// ---------------------------------------------------------------- launch
extern "C" void kernel_launch(void* const* d_in, const int* in_sizes, int n_in,
                              void* d_out, int out_size, void* d_ws, size_t ws_size,
                              hipStream_t stream) {
  const int*   cond_idx = (const int*)d_in[0];
  const float* pert     = (const float*)d_in[1];
  const float* gnn_k    = (const float*)d_in[2];
  const float* w1       = (const float*)d_in[3];
  const float* b1       = (const float*)d_in[4];
  const float* w2       = (const float*)d_in[5];
  const float* b2       = (const float*)d_in[6];
  const int*   adj_row  = (const int*)d_in[7];   // int32! harness demotes int64
  const int*   adj_col  = (const int*)d_in[8];   // int32!
  const float* adj_vals = (const float*)d_in[9];
  const int*   cg_idx   = (const int*)d_in[10];
  const float* cg_mask  = (const float*)d_in[11];
  float* out = (float*)d_out;

  char* w = (char*)d_ws;
  auto alloc = [&](size_t bytes) {
    void* p = w;
    w += (bytes + 255) & ~size_t(255);
    return p;
  };
  constexpr int MT_G = (N_GENES + 127) / 128;   // 157
  constexpr int MT_B = BATCH / 128;             // 128
  char*         aggHi   = (char*)alloc((size_t)MT_G * 4 * 16384);   // 10.3 MB
  char*         aggLo   = (char*)alloc((size_t)MT_G * 4 * 16384);
  float*        embf    = (float*)alloc((size_t)N_GENES * D * 4);   // 20.5 MB
  char*         sumHi   = (char*)alloc((size_t)MT_B * 4 * 16384);   // 8.4 MB
  char*         sumLo   = (char*)alloc((size_t)MT_B * 4 * 16384);
  char*         hHi     = (char*)alloc((size_t)MT_B * 4 * 16384);
  char*         hLo     = (char*)alloc((size_t)MT_B * 4 * 16384);
  char*         wHi     = (char*)alloc((size_t)4 << 17);            // 512 KB
  char*         wLo     = (char*)alloc((size_t)4 << 17);
  unsigned int* edges   = (unsigned int*)alloc((size_t)NNZ * 4);    // 2.56 MB
  int*          cnt     = (int*)alloc((size_t)NB * 4);              // 640 KB
  int*          bptr    = (int*)alloc((size_t)(NB + 4) * 4);
  int*          fill_ctr= (int*)alloc((size_t)NB * 4);
  int*          bsum    = (int*)alloc((size_t)1024 * 4);
  int*          bpre    = (int*)alloc((size_t)1024 * 4);
  float*        ngenes  = (float*)alloc((size_t)BATCH * 4);

  // bf16 source aliases (lifetime-disjoint with their hosts):
  //  pert_bf (10.24MB) = sumHi (8.39MB) + 1.85MB overflow into sumLo.
  //    SAFE: pert_bf written in fused_fill_conv, last read by spmm0;
  //    sumHi/sumLo first written by gather_conditions (after spmm0).
  //  embf_bf (10.24MB) aliases embf (20.5MB): written by L0 gemm, read by
  //    spmm1; embf fp32 rewritten by L1 gemm (stream-ordered after).
  unsigned short* pert_bf = (unsigned short*)sumHi;
  unsigned short* embf_bf = (unsigned short*)embf;

  // 1. bucketed-CSR build (13 graph nodes total)
  hipMemsetAsync(cnt, 0, (size_t)NB * 4, stream);
  count_buckets<<<NNZ / 256, 256, 0, stream>>>(adj_row, adj_col, cnt);
  scan_partial<<<SCAN_BLKS, 256, 0, stream>>>(cnt, bsum);
  scan_mid<<<1, 1024, 0, stream>>>(bsum, bpre);
  scan_final<<<SCAN_BLKS, 256, 0, stream>>>(cnt, bpre, bptr, fill_ctr);
  fused_fill_conv<<<2500 + 128 + 5000, 256, 0, stream>>>(
      adj_row, adj_col, adj_vals, fill_ctr, edges,
      gnn_k, w1, w2, wHi, wLo, pert, (ushort4*)pert_bf);

  // 2. GNN layer 0: agg = A@pert_bf (images); emb1 = relu(agg @ K0) -> bf16
  spmm_csr_img<<<N_GENES / 4, 256, 0, stream>>>(bptr, edges, pert_bf, aggHi, aggLo);
  gemm_bf16x3<E_RELU_BF16><<<2 * MT_G, 256, 0, stream>>>(
      aggHi, aggLo, wHi, wLo, nullptr, nullptr, embf_bf, nullptr, nullptr, nullptr, N_GENES);

  // 3. GNN layer 1: agg = A@emb1_bf (images); emb2 = agg @ K1 -> fp32
  spmm_csr_img<<<N_GENES / 4, 256, 0, stream>>>(bptr, edges, embf_bf, aggHi, aggLo);
  gemm_bf16x3<E_F32><<<2 * MT_G, 256, 0, stream>>>(
      aggHi, aggLo, wHi + (1 << 17), wLo + (1 << 17), nullptr, embf, nullptr, nullptr, nullptr, nullptr, N_GENES);

  // 4. condition gather: summed -> d_out fp32 (final for n<=1) + images + ngenes
  gather_conditions<<<BATCH / 4, 256, 0, stream>>>(cond_idx, cg_idx, cg_mask, embf,
                                                   out, sumHi, sumLo, ngenes);

  // 5. MLP1: h = relu(summed@W1+b1) -> h images
  gemm_bf16x3<E_HIMG><<<2 * MT_B, 256, 0, stream>>>(
      sumHi, sumLo, wHi + (2 << 17), wLo + (2 << 17), b1, nullptr, nullptr, hHi, hLo, nullptr, BATCH);

  // 6. MLP2: rows with n>=2 get relu(h@W2+b2)
  gemm_bf16x3<E_SELECT><<<2 * MT_B, 256, 0, stream>>>(
      hHi, hLo, wHi + (3 << 17), wLo + (3 << 17), b2, out, nullptr, nullptr, nullptr, ngenes, BATCH);
}